// Round 10
// baseline (306.710 us; speedup 1.0000x reference)
//
#include <hip/hip_runtime.h>
#include <hip/hip_bf16.h>

// ---------------- problem constants ----------------
constexpr int BATCH = 8;
constexpr int CIN   = 256;
constexpr int HH    = 64;
constexpr int WW    = 64;
constexpr int NPIX  = HH * WW;        // 4096
constexpr int ICH   = 128;            // init_ch == new_ch

// ---------------- workspace layout (in floats) ----------------
constexpr size_t OFF_XD    = 0;                        // 8*256*16*16 = 524288 f
constexpr size_t OFF_HMEAN = 524288;                   // 256 f
constexpr size_t OFF_WFULL = 524544;                   // 64 f
constexpr size_t OFF_SLOT  = 524608;                   // 64 f (ints)
constexpr size_t OFF_WTB   = 524672;                   // bf16 weights: 1,474,560 us = 737,280 f
constexpr size_t OFF_XBP   = OFF_WTB + 737280;         // bf16 x padded NHWC 8*66*66*256 us = 4,460,544 f
constexpr size_t OFF_X1B   = OFF_XBP + 4460544;        // bf16 x1: 12,582,912 us = 6,291,456 f
// total = 12,013,952 floats = 48.1 MB of d_ws

typedef __bf16  bf16x8 __attribute__((ext_vector_type(8)));
typedef float   f32x4  __attribute__((ext_vector_type(4)));
typedef float   f32x16 __attribute__((ext_vector_type(16)));

__device__ __forceinline__ float silu_f(float v) { return v / (1.f + __expf(-v)); }

__device__ __forceinline__ unsigned short f2bf(float f) {
    return __builtin_bit_cast(unsigned short, __float2bfloat16(f));
}
__device__ __forceinline__ float bf2f(unsigned short u) {
    return __builtin_bit_cast(float, (unsigned)u << 16);
}
__device__ __forceinline__ bf16x8 ld_frag(const ushort* p) {
    uint4 v = *(const uint4*)p;          // ds_read_b128
    return __builtin_bit_cast(bf16x8, v);
}
// async global->LDS DMA, 16B per lane; LDS dest = wave-uniform base + lane*16
__device__ __forceinline__ void gload16(const ushort* g, ushort* l) {
    __builtin_amdgcn_global_load_lds(
        (const __attribute__((address_space(1))) void*)g,
        (__attribute__((address_space(3))) void*)l, 16, 0, 0);
}

// ---------------- K1: 4x4 avg pool  x[8,256,64,64] -> xd[8,256,16,16] ----------------
__global__ void k_avgpool(const float* __restrict__ x, float* __restrict__ xd)
{
    int t = blockIdx.x * 256 + threadIdx.x;
    int jb = t & 3, i = (t >> 2) & 15, c = (t >> 6) & 255, b = t >> 14;
    const float* src = x + ((size_t)(b * CIN + c) * HH + i * 4) * WW + jb * 16;
    float s0 = 0.f, s1 = 0.f, s2 = 0.f, s3 = 0.f;
#pragma unroll
    for (int r = 0; r < 4; ++r) {
        const float4* p = (const float4*)(src + r * WW);
        float4 a = p[0], b4 = p[1], c4 = p[2], d4 = p[3];
        s0 += a.x + a.y + a.z + a.w;
        s1 += b4.x + b4.y + b4.z + b4.w;
        s2 += c4.x + c4.y + c4.z + c4.w;
        s3 += d4.x + d4.y + d4.z + d4.w;
    }
    float4 o;
    o.x = s0 * 0.0625f; o.y = s1 * 0.0625f; o.z = s2 * 0.0625f; o.w = s3 * 0.0625f;
    *(float4*)(xd + ((size_t)(b * CIN + c) * 16 + i) * 16 + jb * 4) = o;
}

// ---------------- K1b: x fp32 NCHW -> bf16 padded NHWC [b][row+1][col+1][cin] --------
__global__ __launch_bounds__(256) void k_xprep(const float* __restrict__ x,
                                               ushort* __restrict__ xbp)
{
    int b = blockIdx.x >> 6, row = blockIdx.x & 63;
    __shared__ ushort tile[64 * 258];    // [col][cin], pad 2 to break bank conflicts
    int tid = threadIdx.x;
    const float* src = x + ((size_t)b * CIN * HH + row) * WW;   // + cin*4096 + col
    for (int k = tid; k < 256 * 64; k += 256) {
        int cin = k >> 6, col = k & 63;                         // coalesced fp32 read
        tile[col * 258 + cin] = f2bf(src[(size_t)cin * NPIX + col]);
    }
    __syncthreads();
    ushort* dst = xbp + ((size_t)(b * 66 + row + 1) * 66 + 1) * 256;
    for (int k = tid; k < 64 * 128; k += 256) {
        int col = k >> 7, cp = (k & 127) * 2;
        unsigned u0 = tile[col * 258 + cp];
        unsigned u1 = tile[col * 258 + cp + 1];
        *(unsigned*)(dst + (size_t)col * 256 + cp) = u0 | (u1 << 16);  // coalesced
    }
}

// ---------------- K2: router conv3x3 (256->32) + BN + SiLU, mean over HW -------------
__global__ __launch_bounds__(256) void k_router_conv(
    const float* __restrict__ xd, const float* __restrict__ Wr1,
    const float* __restrict__ sr1, const float* __restrict__ br1,
    float* __restrict__ hmean)
{
    int b = blockIdx.x >> 5, r = blockIdx.x & 31;
    __shared__ float wl[9 * 256];
    __shared__ float red[256];
    int tid = threadIdx.x;
    for (int k = tid; k < 2304; k += 256) {
        int cin = k / 9, tap = k % 9;
        wl[tap * 256 + cin] = Wr1[r * 2304 + k];
    }
    __syncthreads();
    const float* xb = xd + (size_t)b * CIN * 256;
    int i = tid >> 4, j = tid & 15;
    float acc = 0.f;
#pragma unroll
    for (int kh = 0; kh < 3; ++kh) {
        int ii = i + kh - 1;
        bool oki = (unsigned)ii < 16u;
        int iis = oki ? ii : 0;
#pragma unroll
        for (int kw = 0; kw < 3; ++kw) {
            int jj = j + kw - 1;
            bool ok = oki && ((unsigned)jj < 16u);
            int off = iis * 16 + (((unsigned)jj < 16u) ? jj : 0);
            const float* wt = wl + (kh * 3 + kw) * 256;
            float t = 0.f;
#pragma unroll 8
            for (int cin = 0; cin < 256; ++cin)
                t = fmaf(wt[cin], xb[cin * 256 + off], t);
            if (ok) acc += t;
        }
    }
    float h = silu_f(acc * sr1[r] + br1[r]);
    red[tid] = h;
    __syncthreads();
    for (int st = 128; st > 0; st >>= 1) {
        if (tid < st) red[tid] += red[tid + st];
        __syncthreads();
    }
    if (tid == 0) hmean[b * 32 + r] = red[0] * (1.f / 256.f);
}

// ---------------- K3: router head: 1x1 conv + BN, softmax, top-k, slot compaction ----
__global__ void k_router_final(const float* __restrict__ hmean,
                               const float* __restrict__ Wr2, const float* __restrict__ sr2,
                               const float* __restrict__ br2, const int* __restrict__ topk_p,
                               float* __restrict__ wfull, int* __restrict__ slot)
{
    __shared__ float lg[8][4];
    __shared__ float wf[8][5];
    int tid = threadIdx.x;
    if (tid < 32) {
        int b = tid >> 2, e = tid & 3;
        float a = 0.f;
        for (int r = 0; r < 32; ++r) a += Wr2[e * 32 + r] * hmean[b * 32 + r];
        lg[b][e] = a * sr2[e] + br2[e];
    }
    __syncthreads();
    if (tid < 8) {
        int b = tid;
        float l0 = lg[b][0], l1 = lg[b][1], l2 = lg[b][2], l3 = lg[b][3];
        float mx = fmaxf(fmaxf(l0, l1), fmaxf(l2, l3));
        float e0 = __expf(l0 - mx), e1 = __expf(l1 - mx), e2 = __expf(l2 - mx), e3 = __expf(l3 - mx);
        float sum = e0 + e1 + e2 + e3;
        float w[4] = { e0 / sum, e1 / sum, e2 / sum, e3 / sum };
        int k = topk_p[0];
        if (k > 4) k = 4;
        bool taken[4] = { false, false, false, false };
        float tv[4]; int ti[4]; float tsum = 0.f;
        for (int t = 0; t < k; ++t) {
            float best = -1e30f; int bi = 0;
            for (int e = 0; e < 4; ++e)
                if (!taken[e] && w[e] > best) { best = w[e]; bi = e; }
            taken[bi] = true; tv[t] = best; ti[t] = bi; tsum += best;
        }
        float inv = 1.f / (tsum + 1e-6f);
        float o[4] = { 0.f, 0.f, 0.f, 0.f };
        for (int t = 0; t < k; ++t) o[ti[t]] = tv[t] * inv;
        for (int e = 0; e < 4; ++e) { wf[b][e] = o[e]; wfull[b * 5 + e] = o[e]; }
        wf[b][4] = 1.f; wfull[b * 5 + 4] = 1.f;
    }
    __syncthreads();
    if (tid == 0) {
        int cnt = 0;
        for (int s = 0; s < 5; ++s)
            for (int b = 0; b < 8; ++b)
                slot[s * 8 + b] = (wf[b][s] != 0.f) ? (cnt++) : -1;
    }
}

// ---- Kprep: weights fp32 OIHW -> bf16 [s][och][chunk16][tap][ks2][oc64][8] ----------
// chunk = 16 cins (one 32x32x16 K-step); staging order == linear layout
__global__ void k_wprep16(const float* __restrict__ We_p, const float* __restrict__ Ws_p,
                          ushort* __restrict__ wtb)
{
    int t = blockIdx.x * 256 + threadIdx.x;   // 1,474,560 dest-linear
    int j    = t & 7;
    int oc   = (t >> 3) & 63;
    int ks2  = (t >> 9) & 1;
    int tap  = (t >> 10) % 9;
    int q    = t / 9216;                       // (s*2+och)*16 + chunk
    int chunk = q & 15;
    int och   = (q >> 4) & 1;
    int s     = q >> 5;
    int cin   = chunk * 16 + ks2 * 8 + j;
    int ocg   = och * 64 + oc;
    float v = (s < 4) ? We_p[((size_t)(s * 128 + ocg) * 256 + cin) * 9 + tap]
                      : Ws_p[((size_t)ocg * 256 + cin) * 9 + tap];
    wtb[t] = f2bf(v);
}

// ---------------- K4: primary conv 3x3 (256->128) as bf16 MFMA implicit GEMM ---------
// 8-wave block (512 thr), tile 64 oc x 512 px (16 rows x 32 cols); wave 64 oc x 64 px
// via 2x2 tiles of mfma_f32_32x32x16_bf16 (CK=16/chunk, 16 chunks).
// LDS: w 2x18KB + x 2x19.1KB = 74.3 KB -> 2 blocks/CU if VGPR<=128 (launch_bounds 512,2)
// Staging: exec-masked global_load_lds, uniform 6 issues/wave; vmcnt(0) drains hidden
// by co-resident waves (2-4 waves/SIMD).
__global__ __launch_bounds__(512, 2) void k_primary_mfma(
    const ushort* __restrict__ xbp, const ushort* __restrict__ wtb,
    const float* __restrict__ se_p, const float* __restrict__ be_p,
    const float* __restrict__ ss_p, const float* __restrict__ bs_p,
    const int* __restrict__ slot, ushort* __restrict__ x1b)
{
    int pass = blockIdx.y;
    int sl = slot[pass];
    if (sl < 0) return;
    int s = pass >> 3, b = pass & 7;
    int och = blockIdx.x >> 3;                         // oc half: 0/1
    int pxt = blockIdx.x & 7;                          // px tile: 4 row-tiles x 2 col-tiles
    int row0 = (pxt >> 1) * 16, col0 = (pxt & 1) * 32;

    __shared__ ushort wbuf[2][1152 * 8];               // 2 x 18432 B  [tap][ks2][oc64]
    __shared__ ushort xbuf[2][1224 * 8];               // 2 x 19584 B  [row18][ks2][col34]

    int tid = threadIdx.x;
    int wv = tid >> 6, lane = tid & 63;
    int wr = wv >> 1, wc = wv & 1;                     // wave: 4 rows x 16 cols of px
    int l31 = lane & 31, ks2l = lane >> 5;
    int r2 = (lane >> 4) & 1, c2 = lane & 15;

    const ushort* xslab = xbp + (size_t)b * 66 * 66 * 256;
    const ushort* wslab = wtb + (size_t)(s * 2 + och) * 147456;

    // staging offsets: per wave w covers 144 granules (64+64+16 lanes),
    // x covers 153 granules (64+64+25 lanes); uniform 6 issues/wave
    int woff[3], wldb[3], xoff[3], xldb[3];
#pragma unroll
    for (int it = 0; it < 3; ++it) {
        int wg = wv * 144 + it * 64 + lane;
        if (wg > 1151) wg = 1151;                      // masked-off lanes only
        woff[it] = wg * 8;
        wldb[it] = (wv * 144 + it * 64) * 8;
        int g = wv * 153 + it * 64 + lane;
        if (g > 1223) g = 1223;                        // masked-off lanes only
        int row = g / 68, rem = g % 68;
        int k2 = rem / 34, col = rem % 34;
        xoff[it] = ((row0 + row) * 66 + (col0 + col)) * 256 + k2 * 8;
        xldb[it] = (wv * 153 + it * 64) * 8;
    }

    f32x16 acc[2][2];                                  // [oc-tile mt][n-tile nt]
#pragma unroll
    for (int mt = 0; mt < 2; ++mt)
#pragma unroll
        for (int nt = 0; nt < 2; ++nt)
#pragma unroll
            for (int r = 0; r < 16; ++r) acc[mt][nt][r] = 0.f;

#define STAGE(ch, bf)                                                           \
    {                                                                           \
        const ushort* ws_ = wslab + (size_t)(ch) * 9216;                        \
        gload16(ws_ + woff[0], &wbuf[bf][wldb[0]]);                             \
        gload16(ws_ + woff[1], &wbuf[bf][wldb[1]]);                             \
        if (lane < 16) gload16(ws_ + woff[2], &wbuf[bf][wldb[2]]);              \
        const ushort* xs_ = xslab + (ch) * 16;                                  \
        gload16(xs_ + xoff[0], &xbuf[bf][xldb[0]]);                             \
        gload16(xs_ + xoff[1], &xbuf[bf][xldb[1]]);                             \
        if (lane < 25) gload16(xs_ + xoff[2], &xbuf[bf][xldb[2]]);              \
    }
#define PIPE_BARRIER(N)                                                         \
    asm volatile("s_waitcnt vmcnt(" #N ")" ::: "memory");                       \
    __builtin_amdgcn_sched_barrier(0);                                          \
    __builtin_amdgcn_s_barrier();                                               \
    __builtin_amdgcn_sched_barrier(0);

    STAGE(0, 0)
    PIPE_BARRIER(0)

    for (int ch = 0; ch < 16; ++ch) {
        int cur = ch & 1;
        if (ch < 15) STAGE(ch + 1, cur ^ 1)            // issue DMA before compute
        const ushort* wl = &wbuf[cur][0];
        const ushort* xl = &xbuf[cur][0];
#pragma unroll
        for (int kh = 0; kh < 3; ++kh) {
#pragma unroll
            for (int kw = 0; kw < 3; ++kw) {
                int tap = kh * 3 + kw;
                bf16x8 a0 = ld_frag(wl + (size_t)((tap * 2 + ks2l) * 64 + l31) * 8);
                bf16x8 a1 = ld_frag(wl + (size_t)((tap * 2 + ks2l) * 64 + 32 + l31) * 8);
#pragma unroll
                for (int nt = 0; nt < 2; ++nt) {
                    int row = wr * 4 + nt * 2 + r2 + kh;
                    bf16x8 bf = ld_frag(xl + (size_t)(row * 68 + ks2l * 34 +
                                                      wc * 16 + c2 + kw) * 8);
                    acc[0][nt] = __builtin_amdgcn_mfma_f32_32x32x16_bf16(
                        a0, bf, acc[0][nt], 0, 0, 0);
                    acc[1][nt] = __builtin_amdgcn_mfma_f32_32x32x16_bf16(
                        a1, bf, acc[1][nt], 0, 0, 0);
                }
            }
        }
        if (ch < 15) PIPE_BARRIER(0)                   // drain stage(ch+1); TLP hides
    }
#undef STAGE
#undef PIPE_BARRIER

    // ---- epilogue: BN + SiLU, bf16 store ----
    // D layout (32x32): col=lane&31 (px n), row=(reg&3)+8*(reg>>2)+4*(lane>>5) (oc)
    const float* scale = (s < 4) ? (se_p + s * ICH) : ss_p;
    const float* shift = (s < 4) ? (be_p + s * ICH) : bs_p;
    ushort* outp = x1b + (size_t)sl * (ICH * NPIX);
    int colg = col0 + wc * 16 + c2;
#pragma unroll
    for (int mt = 0; mt < 2; ++mt) {
#pragma unroll
        for (int nt = 0; nt < 2; ++nt) {
            int rowg = row0 + wr * 4 + nt * 2 + r2;
#pragma unroll
            for (int r = 0; r < 16; ++r) {
                int oc = och * 64 + mt * 32 + (r & 3) + 8 * (r >> 2) + 4 * ks2l;
                float v = acc[mt][nt][r] * scale[oc] + shift[oc];
                outp[(size_t)oc * NPIX + rowg * 64 + colg] = f2bf(silu_f(v));
            }
        }
    }
}

// ---------------- K5: depthwise 3x3 + BN + SiLU + weighted combine -> out ------------
__global__ __launch_bounds__(256) void k_cheap(
    const ushort* __restrict__ x1b, const float* __restrict__ We_c,
    const float* __restrict__ se_c, const float* __restrict__ be_c,
    const float* __restrict__ Ws_c, const float* __restrict__ ss_c,
    const float* __restrict__ bs_c, const float* __restrict__ wfull,
    const int* __restrict__ slot, float* __restrict__ out)
{
    int blk = blockIdx.x;
    int b = blk >> 7, c = blk & 127;
    __shared__ float img[3][66][66];                   // 52.3 KB -> 3 blocks/CU
    int tid = threadIdx.x;

    int nact = 0;
    int sls[3], sidx[3];
    float wgts[3];
    for (int s = 0; s < 5; ++s) {
        int sl = slot[s * 8 + b];
        if (sl < 0) continue;
        sls[nact] = sl; sidx[nact] = s;
        wgts[nact] = (s < 4) ? wfull[b * 5 + s] : 1.0f;
        ++nact;
    }

    for (int k = tid; k < 3 * 66 * 66; k += 256) ((float*)img)[k] = 0.f;
    __syncthreads();

#pragma unroll
    for (int a = 0; a < 3; ++a) {
        if (a < nact) {
            const ushort* src = x1b + ((size_t)sls[a] * ICH + c) * NPIX;
            for (int k = tid; k < 1024; k += 256) {
                int i = k >> 4, jc = (k & 15) * 4;
                uint2 u = *(const uint2*)(src + i * 64 + jc);
                img[a][1 + i][1 + jc] = bf2f((unsigned short)(u.x & 0xFFFFu));
                img[a][1 + i][2 + jc] = bf2f((unsigned short)(u.x >> 16));
                img[a][1 + i][3 + jc] = bf2f((unsigned short)(u.y & 0xFFFFu));
                img[a][1 + i][4 + jc] = bf2f((unsigned short)(u.y >> 16));
            }
        }
    }
    __syncthreads();

    float o1[16], o2[16];
#pragma unroll
    for (int t = 0; t < 16; ++t) { o1[t] = 0.f; o2[t] = 0.f; }

#pragma unroll
    for (int a = 0; a < 3; ++a) {
        if (a < nact) {
            int s = sidx[a];
            const float* wp = (s < 4) ? (We_c + (size_t)(s * ICH + c) * 9)
                                      : (Ws_c + (size_t)c * 9);
            float wc0 = wp[0], wc1 = wp[1], wc2 = wp[2], wc3 = wp[3], wc4 = wp[4],
                  wc5 = wp[5], wc6 = wp[6], wc7 = wp[7], wc8 = wp[8];
            float sc = (s < 4) ? se_c[s * ICH + c] : ss_c[c];
            float sh = (s < 4) ? be_c[s * ICH + c] : bs_c[c];
            float wgt = wgts[a];
#pragma unroll
            for (int t = 0; t < 16; ++t) {
                int p = tid + t * 256;
                int i = p >> 6, j = p & 63;
                float center = img[a][1 + i][1 + j];
                float d = wc0 * img[a][i][j];
                d = fmaf(wc1, img[a][i][j + 1], d);
                d = fmaf(wc2, img[a][i][j + 2], d);
                d = fmaf(wc3, img[a][i + 1][j], d);
                d = fmaf(wc4, center, d);
                d = fmaf(wc5, img[a][i + 1][j + 2], d);
                d = fmaf(wc6, img[a][i + 2][j], d);
                d = fmaf(wc7, img[a][i + 2][j + 1], d);
                d = fmaf(wc8, img[a][i + 2][j + 2], d);
                float v = d * sc + sh;
                o1[t] += wgt * center;
                o2[t] += wgt * silu_f(v);
            }
        }
    }

    float* out1 = out + ((size_t)(b * 256) + c) * NPIX;
    float* out2 = out + ((size_t)(b * 256) + 128 + c) * NPIX;
#pragma unroll
    for (int t = 0; t < 16; ++t) {
        int p = tid + t * 256;
        out1[p] = o1[t];
        out2[p] = o2[t];
    }
}

// ---------------- launcher ----------------
extern "C" void kernel_launch(void* const* d_in, const int* in_sizes, int n_in,
                              void* d_out, int out_size, void* d_ws, size_t ws_size,
                              hipStream_t stream)
{
    const float* x    = (const float*)d_in[0];
    const float* Wr1  = (const float*)d_in[1];
    const float* sr1  = (const float*)d_in[2];
    const float* br1  = (const float*)d_in[3];
    const float* Wr2  = (const float*)d_in[4];
    const float* sr2  = (const float*)d_in[5];
    const float* br2  = (const float*)d_in[6];
    const float* We_p = (const float*)d_in[7];
    const float* se_p = (const float*)d_in[8];
    const float* be_p = (const float*)d_in[9];
    const float* We_c = (const float*)d_in[10];
    const float* se_c = (const float*)d_in[11];
    const float* be_c = (const float*)d_in[12];
    const float* Ws_p = (const float*)d_in[13];
    const float* ss_p = (const float*)d_in[14];
    const float* bs_p = (const float*)d_in[15];
    const float* Ws_c = (const float*)d_in[16];
    const float* ss_c = (const float*)d_in[17];
    const float* bs_c = (const float*)d_in[18];
    const int*  topk  = (const int*)d_in[19];
    float* out = (float*)d_out;
    float* ws  = (float*)d_ws;

    float*  xd    = ws + OFF_XD;
    float*  hmean = ws + OFF_HMEAN;
    float*  wfull = ws + OFF_WFULL;
    int*    slot  = (int*)(ws + OFF_SLOT);
    ushort* wtb   = (ushort*)(ws + OFF_WTB);
    ushort* xbp   = (ushort*)(ws + OFF_XBP);
    ushort* x1b   = (ushort*)(ws + OFF_X1B);
    // requires ws_size >= 48.1 MB (round 3 proved >= 58.3 MB works)

    hipMemsetAsync(xbp, 0, (size_t)8 * 66 * 66 * 256 * sizeof(ushort), stream);
    k_avgpool<<<512, 256, 0, stream>>>(x, xd);
    k_xprep<<<512, 256, 0, stream>>>(x, xbp);
    k_wprep16<<<5760, 256, 0, stream>>>(We_p, Ws_p, wtb);
    k_router_conv<<<256, 256, 0, stream>>>(xd, Wr1, sr1, br1, hmean);
    k_router_final<<<1, 64, 0, stream>>>(hmean, Wr2, sr2, br2, topk, wfull, slot);
    k_primary_mfma<<<dim3(16, 40), 512, 0, stream>>>(xbp, wtb, se_p, be_p, ss_p, bs_p, slot, x1b);
    k_cheap<<<1024, 256, 0, stream>>>(x1b, We_c, se_c, be_c, Ws_c, ss_c, bs_c, wfull, slot, out);
}